// Round 4
// baseline (182.133 us; speedup 1.0000x reference)
//
#include <hip/hip_runtime.h>

// ---------------------------------------------------------------------------
// HieraWeatherEmbedding R11: LDS diet 53632 -> 40576 B => 4 blocks/CU, grid
// 1024 runs in ONE fully-resident round (was 2 ragged rounds of 3+1).
//  - Phase B: 6 phases x 2 groups (wpAll 8 slots = 8192 B, was 20 slots).
//  - Gl single-buffer (10240 B): C3 transpose is intra-wave, lp serialized.
//  - apB eliminated: R-GEMM B-frag gathered sce2->regs (used exactly once);
//    sce2 stride 16->12; phantom outg2 row replaced by cndmask-zero B-frag.
//  - p1/p2 unchanged from R10.
// fp32 I/O, bf16 fragments, fp32 accumulate.
// ---------------------------------------------------------------------------

typedef __attribute__((ext_vector_type(8))) short short8;
typedef __attribute__((ext_vector_type(4))) float f32x4;

__constant__ int GOFF[13] = {0,7,14,21,28,35,44,53,62,71,80,97,103};
__constant__ int K5A[12]  = {35,35,35,35,35,45,45,45,45,45,85,30};
__constant__ int SLOTS3[12] = {3,3,3,3,3,3,3,3,3,3,6,2};
__constant__ int FOFFA[12] = {0,3,6,9,12,15,18,21,24,27,30,36};   // slot offsets (total 38)
__constant__ int GSLOT[103] = {
  3,8,13,18,23,28,33,
  4,9,14,19,24,29,34,
  2,7,12,17,22,27,32,
  1,6,11,16,21,26,31,
  0,5,10,15,20,25,30,
  3,8,13,18,23,28,33,38,43,
  4,9,14,19,24,29,34,39,44,
  2,7,12,17,22,27,32,37,42,
  1,6,11,16,21,26,31,36,41,
  0,5,10,15,20,25,30,35,40,
  45,46,47,48,49,50,51,52,53,54,55,56,57,58,59,60,61,
  62,63,64,65,66,67};
__constant__ int GIDX[103] = {
  0,0,0,0,0,0,0, 1,1,1,1,1,1,1, 2,2,2,2,2,2,2, 3,3,3,3,3,3,3, 4,4,4,4,4,4,4,
  5,5,5,5,5,5,5,5,5, 6,6,6,6,6,6,6,6,6, 7,7,7,7,7,7,7,7,7, 8,8,8,8,8,8,8,8,8,
  9,9,9,9,9,9,9,9,9,
  10,10,10,10,10,10,10,10,10,10,10,10,10,10,10,10,10,
  11,11,11,11,11,11};
// tile -> (gi, nt) for the 38 CW2 fragment tiles
__constant__ int TGI[38] = {0,0,0,1,1,1,2,2,2,3,3,3,4,4,4,5,5,5,6,6,6,7,7,7,
                            8,8,8,9,9,9,10,10,10,10,10,10,11,11};
__constant__ int TNT[38] = {0,1,2,0,1,2,0,1,2,0,1,2,0,1,2,0,1,2,0,1,2,0,1,2,
                            0,1,2,0,1,2,0,1,2,3,4,5,0,1};

// compile-time copies for fully-unrolled loops
constexpr int cSLOTS[12] = {3,3,3,3,3,3,3,3,3,3,6,2};
constexpr int cFOFFA[12] = {0,3,6,9,12,15,18,21,24,27,30,36};
constexpr int cK5[12]    = {35,35,35,35,35,45,45,45,45,45,85,30};
constexpr int cGOFFC[12] = {0,7,14,21,28,35,44,53,62,71,80,97};
constexpr int cC0[12]    = {3,4,2,1,0,3,4,2,1,0,45,62};
constexpr int cSTP[12]   = {5,5,5,5,5,5,5,5,5,5,1,1};

// fp32 workspace region (float offsets)
#define QK_GRP 0        // [12][2][128]
#define QK_ENS 3072     // [24][128]
#define QB_GRP 6144     // [12][2]
#define QB_ENS 6176     // [24]
#define CGRP   6208     // [12][128]
#define CENS   7744     // [128]
// byte offsets
#define CWQ_BYTE   43776    // float [103][2][8]
#define MPL_BYTE   50432    // MA: ushort [12][2][8mt][4kt][64][8]  (786432 B)
#define CW2_BYTE   836864   // CW2: ushort [38tile][4kt][64][8]     (155648 B)
#define MEB_BYTE   1623296  // ushort [8mt][8kt][64][8] (65536 B)
#define QKEB_BYTE  1688832  // ushort [2nt][4kt][64][8] (8192 B)
#define FWS_BYTE   1697024  // ushort 304 frags * 512  (311296 B)

__device__ __forceinline__ float bf2f(unsigned short s) {
  return __uint_as_float(((unsigned)s) << 16);
}
__device__ __forceinline__ unsigned short f2bf(float f) {
  unsigned u = __float_as_uint(f);
  u += 0x7fffu + ((u >> 16) & 1u);
  return (unsigned short)(u >> 16);
}

// ---------------------------------------------------------------------------
// P1 (unchanged from R10). Grid 2242 x 256.
// ---------------------------------------------------------------------------
__global__ void hwe_p1(const float* __restrict__ giw, const float* __restrict__ gib,
                       const float* __restrict__ gow, const float* __restrict__ gob,
                       const float* __restrict__ cq,  const float* __restrict__ eq,
                       const float* __restrict__ eiw, const float* __restrict__ eib,
                       const float* __restrict__ eow, const float* __restrict__ eob,
                       const float* __restrict__ cw,  const float* __restrict__ cb,
                       const float* __restrict__ ce,
                       float* __restrict__ wsf, unsigned short* __restrict__ MA,
                       unsigned short* __restrict__ CW2,
                       unsigned short* __restrict__ MeB, unsigned short* __restrict__ Fws) {
  int blk = blockIdx.x, tid = threadIdx.x;
  int wave = tid >> 6, lane = tid & 63;
  if (blk < 48) {
    __shared__ float qf[64];
    bool ens = blk >= 24;
    int bi = ens ? blk - 24 : blk;
    int i = bi >> 1, h = bi & 1;
    const float* W  = ens ? eiw : giw + i*49152;
    const float* bv = ens ? eib : gib + i*384;
    const float* qv = ens ? eq + i*128 : cq + i*128;
    for (int it = 0; it < 16; ++it) {
      int dp = it*4 + wave;
      const float* wrow = W + (h*64 + dp)*128;
      float acc = wrow[lane]*qv[lane] + wrow[lane+64]*qv[lane+64];
#pragma unroll
      for (int off = 32; off > 0; off >>= 1) acc += __shfl_down(acc, off);
      if (lane == 0) qf[dp] = acc + bv[h*64 + dp];
    }
    __syncthreads();
    if (tid < 128) {
      int e = tid;
      const float* Wk = W + (128 + h*64)*128 + e;
      float a0=0.f,a1=0.f,a2=0.f,a3=0.f;
      for (int dp = 0; dp < 64; dp += 4) {
        a0 += qf[dp+0] * Wk[(dp+0)*128];
        a1 += qf[dp+1] * Wk[(dp+1)*128];
        a2 += qf[dp+2] * Wk[(dp+2)*128];
        a3 += qf[dp+3] * Wk[(dp+3)*128];
      }
      wsf[(ens ? QK_ENS : QK_GRP) + bi*128 + e] = (a0+a1)+(a2+a3);
    }
    if (wave == 3) {
      float acc = qf[lane] * bv[128 + h*64 + lane];
#pragma unroll
      for (int off = 32; off > 0; off >>= 1) acc += __shfl_down(acc, off);
      if (lane == 0) wsf[(ens ? QB_ENS : QB_GRP) + bi] = acc;
    }
  } else if (blk < 1584) {               // MA bf16 A-frags
    int b2 = blk - 48;
    int gi = b2 >> 7, r = b2 & 127;
    int ep = tid, h = ep >> 7, e = ep & 127;
    const float* wo = gow + gi*16384 + r*128 + h*64;
    const float* wv = giw + gi*49152 + (256 + h*64)*128 + e;
    float a0=0.f,a1=0.f,a2=0.f,a3=0.f;
    for (int hd = 0; hd < 64; hd += 4) {
      a0 += wo[hd+0] * wv[(hd+0)*128];
      a1 += wo[hd+1] * wv[(hd+1)*128];
      a2 += wo[hd+2] * wv[(hd+2)*128];
      a3 += wo[hd+3] * wv[(hd+3)*128];
    }
    float acc = (a0+a1)+(a2+a3);
    int mt = r >> 4, lr = r & 15, kt = e >> 5, q = (e >> 3) & 3, j = e & 7;
    MA[(((gi*2 + h)*8 + mt)*4 + kt)*512 + (q*16 + lr)*8 + j] = f2bf(acc);
  } else if (blk < 1712) {               // MeB A-frag
    int f2 = (blk - 1584)*256 + tid;
    int r = f2 >> 8, ep = f2 & 255;
    int h = ep >> 7, e = ep & 127;
    const float* wo = eow + r*128 + h*64;
    const float* wv = eiw + (256 + h*64)*128 + e;
    float a0=0.f,a1=0.f,a2=0.f,a3=0.f;
    for (int hd = 0; hd < 64; hd += 4) {
      a0 += wo[hd+0] * wv[(hd+0)*128];
      a1 += wo[hd+1] * wv[(hd+1)*128];
      a2 += wo[hd+2] * wv[(hd+2)*128];
      a3 += wo[hd+3] * wv[(hd+3)*128];
    }
    float acc = (a0+a1)+(a2+a3);
    int mt = r >> 4, lr = r & 15, kt = ep >> 5, q = (ep >> 3) & 3, j = ep & 7;
    MeB[((mt*8 + kt)*64 + (q*16 + lr))*8 + j] = f2bf(acc);
  } else if (blk < 2096) {               // CGRP
    int id = (blk - 1712)*4 + wave;
    int i = id >> 7, d = id & 127;
    const float* wrow = gow + i*16384 + d*128;
    const float* bvv = gib + i*384 + 256;
    float acc = wrow[lane]*bvv[lane] + wrow[lane+64]*bvv[lane+64];
#pragma unroll
    for (int off = 32; off > 0; off >>= 1) acc += __shfl_down(acc, off);
    if (lane == 0) wsf[CGRP + id] = acc + gob[i*128 + d];
  } else if (blk < 2128) {               // CENS
    int d = (blk - 2096)*4 + wave;
    const float* wrow = eow + d*128;
    const float* bvv = eib + 256;
    float acc = wrow[lane]*bvv[lane] + wrow[lane+64]*bvv[lane+64];
#pragma unroll
    for (int off = 32; off > 0; off >>= 1) acc += __shfl_down(acc, off);
    if (lane == 0) wsf[CENS + d] = acc + eob[d];
  } else if (blk < 2166) {               // CW2 B-frags
    int tile = blk - 2128;
    int gi = TGI[tile], nt = TNT[tile];
    int kt = tid >> 6;
    int l15b = tid & 15, quadb = (tid >> 4) & 3;
    int k = nt*16 + l15b;
    int e = kt*32 + quadb*8;
    unsigned short vv[8];
    if (k < K5A[gi]) {
      int q = (k*205) >> 10;
      int pp = k - q*5;
      int s = GSLOT[GOFF[gi] + q];
      int v = (s < 45) ? s : s + 20;
      if (pp < 4) {
        const float* src = cw + (v*4 + pp)*128 + e;
#pragma unroll
        for (int j = 0; j < 8; ++j) vv[j] = f2bf(src[j]);
      } else {
        const float* b1 = cb + v*128 + e;
        const float* c1 = ce + v*128 + e;
#pragma unroll
        for (int j = 0; j < 8; ++j) vv[j] = f2bf(b1[j] + c1[j]);
      }
    } else {
#pragma unroll
      for (int j = 0; j < 8; ++j) vv[j] = 0;
    }
    unsigned short* dst = CW2 + (tile*4 + kt)*512 + (tid & 63)*8;
#pragma unroll
    for (int j = 0; j < 8; ++j) dst[j] = vv[j];
  } else {                               // F-zero
    int idx = (blk - 2166)*256 + tid;
    if (idx < 19456) ((uint4*)Fws)[idx] = (uint4){0,0,0,0};
  }
}

// ---------------------------------------------------------------------------
// P2 (unchanged from R10). Grid 260 x 256.
// ---------------------------------------------------------------------------
__global__ void hwe_p2(const float* __restrict__ cw, const float* __restrict__ cb,
                       const float* __restrict__ ce,
                       const unsigned short* __restrict__ MA,
                       const unsigned short* __restrict__ CW2,
                       const float* __restrict__ wsf,
                       unsigned short* __restrict__ Fws,
                       unsigned short* __restrict__ qkeB, float* __restrict__ cwq) {
  int blk = blockIdx.x, tid = threadIdx.x;
  int wave = tid >> 6, lane = tid & 63;
  int quad = lane >> 4, l15 = lane & 15;
  if (blk < 192) {
    int gi = blk >> 4, h = (blk >> 3) & 1, mt = blk & 7;
    int K5 = K5A[gi], S = SLOTS3[gi];
    const unsigned short* MAp = MA + (((gi*2 + h)*8 + mt)*4)*512 + lane*8;
    short8 a[4];
#pragma unroll
    for (int kt = 0; kt < 4; ++kt)
      a[kt] = *(const short8*)(MAp + kt*512);
    for (int nt = wave; nt < S; nt += 4) {
      const unsigned short* Bp = CW2 + (FOFFA[gi] + nt)*2048 + lane*8;
      f32x4 acc = {0.f,0.f,0.f,0.f};
#pragma unroll
      for (int kt = 0; kt < 4; ++kt) {
        short8 b = *(const short8*)(Bp + kt*512);
        acc = __builtin_amdgcn_mfma_f32_16x16x32_bf16(a[kt], b, acc, 0, 0, 0);
      }
      int k = nt*16 + l15;
      if (k < K5) {
        int kpp = h*K5 + k;
        int base = (FOFFA[gi]*8 + mt*S + (kpp >> 5))*512
                 + ((kpp >> 3) & 3)*128 + (kpp & 7);
#pragma unroll
        for (int reg = 0; reg < 4; ++reg) {
          int rr = quad*4 + reg;
          Fws[base + rr*8] = f2bf(acc[reg]);
        }
      }
    }
  } else if (blk < 208) {
    int f4 = (blk - 192)*256 + tid;
    int ln = (f4 >> 3) & 63, j = f4 & 7;
    int th = ((f4 >> 11) & 1)*16 + (ln & 15);
    int kt = (f4 >> 9) & 3;
    float val = (th < 24) ? wsf[QK_ENS + th*128 + kt*32 + (ln >> 4)*8 + j] : 0.f;
    qkeB[f4] = f2bf(val);
  } else {
    int wid = (blk - 208)*4 + wave;
    if (wid < 206) {
      int gg = wid >> 1, h = wid & 1;
      int gi = GIDX[gg];
      int s = GSLOT[gg];
      int v = (s < 45) ? s : s + 20;
      const float* qk = wsf + QK_GRP + (gi*2 + h)*128;
      float q0 = qk[lane], q1 = qk[lane + 64];
      float a[5];
#pragma unroll
      for (int pp = 0; pp < 4; ++pp)
        a[pp] = cw[(v*4 + pp)*128 + lane]*q0 + cw[(v*4 + pp)*128 + lane + 64]*q1;
      a[4] = (cb[v*128 + lane] + ce[v*128 + lane])*q0 +
             (cb[v*128 + lane + 64] + ce[v*128 + lane + 64])*q1;
#pragma unroll
      for (int off = 32; off > 0; off >>= 1)
#pragma unroll
        for (int kk = 0; kk < 5; ++kk) a[kk] += __shfl_down(a[kk], off);
      if (lane == 0) {
        float* o = cwq + (gg*2 + h)*8;
        o[0] = a[0]*0.125f; o[1] = a[1]*0.125f; o[2] = a[2]*0.125f; o[3] = a[3]*0.125f;
        o[4] = (a[4] + wsf[QB_GRP + gi*2 + h]) * 0.125f;
      }
    }
  }
}

// ---------------------------------------------------------------------------
// Main kernel. grid 1024, block 256 (4 waves), 8 patches/block.
// LDS 40576 B -> 4 blocks/CU, grid fully resident in ONE round.
//   Phase A/B: xpB@0 (4352), scb@4352 (3328), wpAll@7680 (8 slots, 8192)
//   outg2@15872 [96][128]us 24576, dual-key swizzle ch^=((row>>3)^row)&7
//   C overlays: Gl@0 [128][40]us 10240 (single buffer, intra-wave);
//               sce2@10240 [192][12]us 4608
//   stats@40448 float[2][16]
// ---------------------------------------------------------------------------
__global__ __launch_bounds__(256, 4) void hwe_main(
    const float* __restrict__ x,
    const float* __restrict__ lgam, const float* __restrict__ lbet,
    const float* __restrict__ wsf,  const float* __restrict__ cwq,
    const unsigned short* __restrict__ Fws, const unsigned short* __restrict__ MeB,
    const unsigned short* __restrict__ qkeB,
    float* __restrict__ out) {
  __shared__ __align__(16) unsigned char smem[40576];
  unsigned short* xpB   = (unsigned short*)(smem);
  unsigned short* scb   = (unsigned short*)(smem + 4352);
  unsigned short* wpAll = (unsigned short*)(smem + 7680);
  unsigned short* Gl    = (unsigned short*)(smem);          // C3 overlay
  unsigned short* sce2  = (unsigned short*)(smem + 10240);  // C overlay
  unsigned short* outg2 = (unsigned short*)(smem + 15872);
  float*          stats = (float*)(smem + 40448);           // [2][16]

  const int tid  = threadIdx.x;
  const int wave = tid >> 6;
  const int lane = tid & 63;
  const int quad = lane >> 4;
  const int l15  = lane & 15;

  const int hi   = blockIdx.x >> 4;
  const int wib  = (blockIdx.x & 15) << 3;
  const int nbase = hi*128 + wib;

  // ---- A1: pixels (float2-vectorized) ----
  for (int idx = tid; idx < 1088; idx += 256) {
    int c2 = idx & 7, r = (idx >> 3) & 1, s = idx >> 4;
    int v = (s < 45) ? s : s + 20;
    const float2 xv = *(const float2*)(x + (v*128 + 2*hi + r)*256 + 2*wib + c2*2);
    unsigned pk = (unsigned)f2bf(xv.x) | ((unsigned)f2bf(xv.y) << 16);
    *(unsigned*)(xpB + (c2*68 + s)*4 + r*2) = pk;
  }
  __syncthreads();

  // ---- A2: group scores via cwq fold ----
  for (int idx = tid; idx < 1648; idx += 256) {
    int h = idx & 1, p = (idx >> 1) & 7, gg = idx >> 4;
    int s = GSLOT[gg];
    const float* c = cwq + (gg*2 + h)*8;
    const unsigned short* xr = xpB + (p*68 + s)*4;
    float acc = c[4] + bf2f(xr[0])*c[0] + bf2f(xr[1])*c[1]
                     + bf2f(xr[2])*c[2] + bf2f(xr[3])*c[3];
    scb[(p*2 + h)*104 + gg] = f2bf(acc);
  }
  __syncthreads();

  // ---- A3: softmax per (p,h,group) — register-resident ----
  if (tid < 192) {
    int gi = tid % 12, h = (tid / 12) & 1, p = tid / 24;
    int go = GOFF[gi], G = GOFF[gi+1] - go;
    unsigned short* row = scb + (p*2 + h)*104 + go;
    float ev[17];
    float m = -1e30f;
#pragma unroll
    for (int g = 0; g < 17; ++g) {
      ev[g] = (g < G) ? bf2f(row[g]) : -1e30f;
      m = fmaxf(m, ev[g]);
    }
    float ssum = 0.f;
#pragma unroll
    for (int g = 0; g < 17; ++g) {
      float e = __expf(ev[g] - m);
      ev[g] = e;
      if (g < G) ssum += e;
    }
    float inv = 1.f / ssum;
#pragma unroll
    for (int g = 0; g < 17; ++g)
      if (g < G) row[g] = f2bf(ev[g] * inv);
  }
  __syncthreads();

  // ---- Phase B: 6 phases x 2 groups; F-folded GEMM per group ----
  {
    short8 fA[6], fB[6];
    float4 cgA, cgB;
    auto fws_issue = [&](int gi, int mh, short8 (&buf)[6], float4& cg) {
      int S = cSLOTS[gi];
      int mt = mh*4 + wave;
      const unsigned short* fp = Fws + (cFOFFA[gi]*8 + mt*S)*512 + lane*8;
#pragma unroll
      for (int kt = 0; kt < 6; ++kt)
        if (kt < S) buf[kt] = *(const short8*)(fp + kt*512);
      cg = *(const float4*)(wsf + CGRP + gi*128 + mt*16 + quad*4);
    };
    auto fws_compute = [&](int gi, int mh, int lbase, short8 (&buf)[6],
                           const float4& cg) {
      int S = cSLOTS[gi];
      int mt = mh*4 + wave;
      f32x4 acc = {0.f,0.f,0.f,0.f};
#pragma unroll
      for (int kt = 0; kt < 6; ++kt)
        if (kt < S) {
          short8 b = *(const short8*)(wpAll + (lbase + kt)*512 + lane*8);
          acc = __builtin_amdgcn_mfma_f32_16x16x32_bf16(buf[kt], b, acc, 0, 0, 0);
        }
      if (l15 < 8) {
        int p = l15;
        int rb = mt*16 + quad*4;
        unsigned short t0 = f2bf(acc[0] + cg.x);
        unsigned short t1 = f2bf(acc[1] + cg.y);
        unsigned short t2 = f2bf(acc[2] + cg.z);
        unsigned short t3 = f2bf(acc[3] + cg.w);
        uint2 w;
        w.x = (unsigned)t0 | ((unsigned)t1 << 16);
        w.y = (unsigned)t2 | ((unsigned)t3 << 16);
        int row = gi*8 + p;
        int ch = (rb >> 3) ^ ((gi ^ p) & 7);      // dual-key swizzle
        *(uint2*)(outg2 + row*128 + ch*8 + (rb & 7)) = w;
      }
    };

    fws_issue(0, 0, fA, cgA);    // prologue prefetch

#pragma unroll
    for (int ph = 0; ph < 6; ++ph) {
      const int g0 = 2*ph;
      const int S0 = cSLOTS[g0];
      const int nsl = S0 + cSLOTS[g0+1];

      // fused position-major fill (2-group decode)
      {
        const int nposs = nsl * 512;
        for (int pos = tid*4; pos < nposs; pos += 1024) {
          int pf = (pos >> 3) & 15;
          uint2 w2 = {0u, 0u};
          if (pf < 8) {
            int ls = pos >> 9;
            int qd = (pos >> 7) & 3;
            int j0 = pos & 7;
            int p  = pf;
            bool gsel = (ls >= S0);
            int lsl   = gsel ? ls - S0 : ls;
            int K5    = gsel ? cK5[g0+1]    : cK5[g0];
            int goffB = gsel ? cGOFFC[g0+1] : cGOFFC[g0];
            int c0    = gsel ? cC0[g0+1]    : cC0[g0];
            int stp   = gsel ? cSTP[g0+1]   : cSTP[g0];
            int kbase = lsl*32 + qd*8 + j0;
            unsigned short vv[4];
#pragma unroll
            for (int jj = 0; jj < 4; ++jj) {
              int kpp = kbase + jj;
              int h = (kpp >= K5) ? 1 : 0;
              int k = kpp - (h ? K5 : 0);
              int q = (k*205) >> 10;
              int pp = k - q*5;
              int gg = goffB + q;
              int s = c0 + q*stp;
              float a  = bf2f(scb[(p*2 + h)*104 + gg]);
              float xv = bf2f(xpB[(p*68 + s)*4 + pp]);
              float val = (pp < 4) ? a * xv : a;
              if (kpp >= 2*K5) val = 0.f;
              vv[jj] = f2bf(val);
            }
            w2.x = (unsigned)vv[0] | ((unsigned)vv[1] << 16);
            w2.y = (unsigned)vv[2] | ((unsigned)vv[3] << 16);
          }
          *(uint2*)(wpAll + pos) = w2;
        }
      }
      __syncthreads();                       // fill visible

      fws_issue(g0+0, 1, fB, cgB);
      fws_compute(g0+0, 0, 0,  fA, cgA);
      fws_issue(g0+1, 0, fA, cgA);
      fws_compute(g0+0, 1, 0,  fB, cgB);
      fws_issue(g0+1, 1, fB, cgB);
      fws_compute(g0+1, 0, S0, fA, cgA);
      if (ph < 5) fws_issue(g0+2, 0, fA, cgA);   // cross-phase prefetch
      fws_compute(g0+1, 1, S0, fB, cgB);
      __syncthreads();                       // wpAll consumed
    }
  }

  // preload cens + MeB fragments early (hide latency under C1/C2)
  float cens0[4], cens1[4];
  {
    float4 c0 = *(const float4*)(wsf + CENS + (wave*2 + 0)*16 + quad*4);
    float4 c1 = *(const float4*)(wsf + CENS + (wave*2 + 1)*16 + quad*4);
    cens0[0]=c0.x; cens0[1]=c0.y; cens0[2]=c0.z; cens0[3]=c0.w;
    cens1[0]=c1.x; cens1[1]=c1.y; cens1[2]=c1.z; cens1[3]=c1.w;
  }
  short8 meAr[16];   // [mi][h][kt]
#pragma unroll
  for (int mi = 0; mi < 2; ++mi)
#pragma unroll
    for (int h = 0; h < 2; ++h)
#pragma unroll
      for (int kt = 0; kt < 4; ++kt)
        meAr[(mi*2 + h)*4 + kt] =
          *(const short8*)(MeB + (((wave*2 + mi)*8 + h*4 + kt)*64 + lane)*8);

  // ---- C1: ens scores GEMM (M=96 rows (s,p), N=24 (t,h), K=128) ----
#pragma unroll
  for (int ti = 0; ti < 3; ++ti) {
    int T = wave*3 + ti;
    int mtp = T >> 1, ntp = T & 1;
    int rowA = mtp*16 + l15;
    int sx = ((rowA >> 3) ^ rowA) & 7;
    f32x4 acc = {0.f,0.f,0.f,0.f};
#pragma unroll
    for (int kt = 0; kt < 4; ++kt) {
      short8 a = *(const short8*)(outg2 + rowA*128 + (((kt*4 + quad) ^ sx) << 3));
      short8 b = *(const short8*)(qkeB + ((ntp*4 + kt)*64 + lane)*8);
      acc = __builtin_amdgcn_mfma_f32_16x16x32_bf16(a, b, acc, 0, 0, 0);
    }
    int th = ntp*16 + l15;
    if (th < 24) {
      float qb = wsf[QB_ENS + th];
#pragma unroll
      for (int reg = 0; reg < 4; ++reg) {
        int rowE = mtp*16 + quad*4 + reg;
        sce2[((rowE & 7)*24 + th)*12 + (rowE >> 3)] = f2bf((acc[reg] + qb) * 0.125f);
      }
    }
  }
  __syncthreads();

  // ---- C2: softmax over s per (p, t, h) — register-resident ----
  if (tid < 192) {
    unsigned short* row = sce2 + tid*12;
    float ev[12];
    float m = -1e30f;
#pragma unroll
    for (int s = 0; s < 12; ++s) { ev[s] = bf2f(row[s]); m = fmaxf(m, ev[s]); }
    float ssum = 0.f;
#pragma unroll
    for (int s = 0; s < 12; ++s) { float e = __expf(ev[s] - m); ev[s] = e; ssum += e; }
    float inv = 1.f / ssum;
#pragma unroll
    for (int s = 0; s < 12; ++s) row[s] = f2bf(ev[s] * inv);
  }
  __syncthreads();

  // ---- C3: 2 patches/period: G-GEMM -> Gl transpose (intra-wave, single
  //      buffer) -> bfrag gather from sce2 -> R-GEMM -> register LayerNorm ----
  for (int pp2 = 0; pp2 < 4; ++pp2) {
    f32x4 g[2][2][2];  // [lp][mi][h]
#pragma unroll
    for (int lp = 0; lp < 2; ++lp)
#pragma unroll
      for (int mi = 0; mi < 2; ++mi)
#pragma unroll
        for (int h = 0; h < 2; ++h) g[lp][mi][h] = (f32x4){0.f,0.f,0.f,0.f};
#pragma unroll
    for (int lp = 0; lp < 2; ++lp) {
      int p = pp2*2 + lp;
      int brow = (l15 < 12) ? (l15*8 + p) : 0;   // clamp; zeroed below
      int sx = ((brow >> 3) ^ brow) & 7;
#pragma unroll
      for (int h = 0; h < 2; ++h) {
#pragma unroll
        for (int kt = 0; kt < 4; ++kt) {
          short8 b = *(const short8*)(outg2 + brow*128 + (((kt*4 + quad) ^ sx) << 3));
          if (l15 >= 12) b = (short8){0,0,0,0,0,0,0,0};
          g[lp][0][h] = __builtin_amdgcn_mfma_f32_16x16x32_bf16(
              meAr[(0*2 + h)*4 + kt], b, g[lp][0][h], 0, 0, 0);
          g[lp][1][h] = __builtin_amdgcn_mfma_f32_16x16x32_bf16(
              meAr[(1*2 + h)*4 + kt], b, g[lp][1][h], 0, 0, 0);
        }
      }
    }

    f32x4 rr[2][2];
    float s1[2] = {0.f, 0.f}, s2[2] = {0.f, 0.f};
#pragma unroll
    for (int lp = 0; lp < 2; ++lp) {
      int p = pp2*2 + lp;
      // write G to Gl (single buffer; intra-wave rows wave*32..wave*32+31)
#pragma unroll
      for (int mi = 0; mi < 2; ++mi)
#pragma unroll
        for (int h = 0; h < 2; ++h)
#pragma unroll
          for (int reg = 0; reg < 4; ++reg) {
            int r = (wave*2 + mi)*16 + quad*4 + reg;
            Gl[r*40 + h*16 + l15] = f2bf(g[lp][mi][h][reg]);
          }
      // read A-frags back (same wave; compiler orders via lgkmcnt)
      short8 af0 = *(const short8*)(Gl + ((wave*2 + 0)*16 + l15)*40 + quad*8);
      short8 af1 = *(const short8*)(Gl + ((wave*2 + 1)*16 + l15)*40 + quad*8);
      // bfrag gather from sce2: lane (t=l15, qd=quad); h=qd>>1, s=(qd&1)*8+j
      union { short8 s8; uint4 u4; } bu;
      {
        const unsigned short* sp = sce2 + (p*24 + l15*2 + (quad >> 1))*12 + (quad & 1)*8;
        uint2 lo = *(const uint2*)(sp);
        uint2 hi2 = *(const uint2*)(sp + 4);
        if (quad & 1) { hi2.x = 0u; hi2.y = 0u; }          // s=12..15 -> 0
        if (l15 >= 12) { lo.x = 0u; lo.y = 0u; hi2.x = 0u; hi2.y = 0u; }
        bu.u4.x = lo.x; bu.u4.y = lo.y; bu.u4.z = hi2.x; bu.u4.w = hi2.y;
      }
#pragma unroll
      for (int mi = 0; mi < 2; ++mi) {
        f32x4 acc = {0.f,0.f,0.f,0.f};
        acc = __builtin_amdgcn_mfma_f32_16x16x32_bf16(mi ? af1 : af0, bu.s8,
                                                      acc, 0, 0, 0);
#pragma unroll
        for (int reg = 0; reg < 4; ++reg)
          acc[reg] += (mi ? cens1[reg] : cens0[reg]);
        rr[lp][mi] = acc;
        if (l15 < 12) {
#pragma unroll
          for (int reg = 0; reg < 4; ++reg) {
            float v = acc[reg];
            s1[lp] += v; s2[lp] += v*v;
          }
        }
      }
    }
#pragma unroll
    for (int off = 32; off > 0; off >>= 1) {
#pragma unroll
      for (int lp = 0; lp < 2; ++lp) {
        s1[lp] += __shfl_xor(s1[lp], off);
        s2[lp] += __shfl_xor(s2[lp], off);
      }
    }
    int sb = (pp2 & 1) << 4;               // stats double-buffer
    if (lane == 0) {
#pragma unroll
      for (int lp = 0; lp < 2; ++lp) {
        stats[sb + lp*4 + wave] = s1[lp];
        stats[sb + 8 + lp*4 + wave] = s2[lp];
      }
    }
    __syncthreads();
#pragma unroll
    for (int lp = 0; lp < 2; ++lp) {
      float t1 = stats[sb+lp*4+0] + stats[sb+lp*4+1] + stats[sb+lp*4+2] + stats[sb+lp*4+3];
      float t2 = stats[sb+8+lp*4+0] + stats[sb+8+lp*4+1] + stats[sb+8+lp*4+2] + stats[sb+8+lp*4+3];
      float mean = t1 * (1.f/1536.f);
      float var  = t2 * (1.f/1536.f) - mean*mean;
      float rstd = rsqrtf(var + 1e-5f);
      if (l15 < 12) {
        long nrow = (long)(nbase + pp2*2 + lp) * 1536;
#pragma unroll
        for (int mi = 0; mi < 2; ++mi) {
          int rb = (wave*2 + mi)*16 + quad*4;
          int j = l15*128 + rb;
          float4 gm = *(const float4*)(lgam + j);
          float4 bt = *(const float4*)(lbet + j);
          float4 o;
          o.x = (rr[lp][mi][0] - mean)*rstd*gm.x + bt.x;
          o.y = (rr[lp][mi][1] - mean)*rstd*gm.y + bt.y;
          o.z = (rr[lp][mi][2] - mean)*rstd*gm.z + bt.z;
          o.w = (rr[lp][mi][3] - mean)*rstd*gm.w + bt.w;
          *(float4*)(out + nrow + j) = o;
        }
      }
    }
    // no period-end barrier: stats double-buffered, Gl intra-wave
  }
}

// ---------------------------------------------------------------------------
extern "C" void kernel_launch(void* const* d_in, const int* in_sizes, int n_in,
                              void* d_out, int out_size, void* d_ws, size_t ws_size,
                              hipStream_t stream) {
  const float* x   = (const float*)d_in[0];
  const float* cw  = (const float*)d_in[1];
  const float* cb  = (const float*)d_in[2];
  const float* ce  = (const float*)d_in[3];
  const float* cq  = (const float*)d_in[4];
  const float* giw = (const float*)d_in[5];
  const float* gib = (const float*)d_in[6];
  const float* gow = (const float*)d_in[7];
  const float* gob = (const float*)d_in[8];
  const float* eq  = (const float*)d_in[9];
  const float* eiw = (const float*)d_in[10];
  const float* eib = (const float*)d_in[11];
  const float* eow = (const float*)d_in[12];
  const float* eob = (const float*)d_in[13];
  const float* lg  = (const float*)d_in[14];
  const float* lb  = (const float*)d_in[15];

  float* wsf = (float*)d_ws;
  float* cwq = (float*)((char*)d_ws + CWQ_BYTE);
  unsigned short* MA   = (unsigned short*)((char*)d_ws + MPL_BYTE);
  unsigned short* CW2  = (unsigned short*)((char*)d_ws + CW2_BYTE);
  unsigned short* MeB  = (unsigned short*)((char*)d_ws + MEB_BYTE);
  unsigned short* qkeB = (unsigned short*)((char*)d_ws + QKEB_BYTE);
  unsigned short* Fws  = (unsigned short*)((char*)d_ws + FWS_BYTE);

  hwe_p1<<<2242, 256, 0, stream>>>(giw, gib, gow, gob, cq, eq, eiw, eib, eow, eob,
                                   cw, cb, ce, wsf, MA, CW2, MeB, Fws);
  hwe_p2<<<260, 256, 0, stream>>>(cw, cb, ce, MA, CW2, wsf, Fws, qkeB, cwq);
  hwe_main<<<1024, 256, 0, stream>>>(x, lg, lb, wsf, cwq, Fws, MeB, qkeB,
                                     (float*)d_out);
}

// Round 5
// 173.835 us; speedup vs baseline: 1.0477x; 1.0477x over previous
//
#include <hip/hip_runtime.h>

// ---------------------------------------------------------------------------
// HieraWeatherEmbedding R12: task-major wpAll fill.
//  R11's position-major fill did 8 scalar ds_read_u16 + ~48 VALU per 4
//  values (re-reading a and pixels per element). The fill is factorized:
//  val(kpp,p) = a(p,h,gg) * xv(p,s,pp), 5 consecutive kpp share one a and
//  one contiguous b64 pixel quad. New fill: task = (gg,h,p) -> 1 u16 read +
//  1 b64 read + 5 u16 writes (+1 VALU-cheap decode). ~10x fewer LDS ops.
//  Tail kpp (>=2*K5) zeroed by a precise disjoint pass (no extra barrier);
//  p>=8 garbage columns provably discarded (only l15<8 stored; F rows zero
//  the K-tail). Everything else identical to R11 (75 us main).
// fp32 I/O, bf16 fragments, fp32 accumulate.
// ---------------------------------------------------------------------------

typedef __attribute__((ext_vector_type(8))) short short8;
typedef __attribute__((ext_vector_type(4))) float f32x4;

__constant__ int GOFF[13] = {0,7,14,21,28,35,44,53,62,71,80,97,103};
__constant__ int K5A[12]  = {35,35,35,35,35,45,45,45,45,45,85,30};
__constant__ int SLOTS3[12] = {3,3,3,3,3,3,3,3,3,3,6,2};
__constant__ int FOFFA[12] = {0,3,6,9,12,15,18,21,24,27,30,36};   // slot offsets (total 38)
__constant__ int GSLOT[103] = {
  3,8,13,18,23,28,33,
  4,9,14,19,24,29,34,
  2,7,12,17,22,27,32,
  1,6,11,16,21,26,31,
  0,5,10,15,20,25,30,
  3,8,13,18,23,28,33,38,43,
  4,9,14,19,24,29,34,39,44,
  2,7,12,17,22,27,32,37,42,
  1,6,11,16,21,26,31,36,41,
  0,5,10,15,20,25,30,35,40,
  45,46,47,48,49,50,51,52,53,54,55,56,57,58,59,60,61,
  62,63,64,65,66,67};
__constant__ int GIDX[103] = {
  0,0,0,0,0,0,0, 1,1,1,1,1,1,1, 2,2,2,2,2,2,2, 3,3,3,3,3,3,3, 4,4,4,4,4,4,4,
  5,5,5,5,5,5,5,5,5, 6,6,6,6,6,6,6,6,6, 7,7,7,7,7,7,7,7,7, 8,8,8,8,8,8,8,8,8,
  9,9,9,9,9,9,9,9,9,
  10,10,10,10,10,10,10,10,10,10,10,10,10,10,10,10,10,
  11,11,11,11,11,11};
// tile -> (gi, nt) for the 38 CW2 fragment tiles
__constant__ int TGI[38] = {0,0,0,1,1,1,2,2,2,3,3,3,4,4,4,5,5,5,6,6,6,7,7,7,
                            8,8,8,9,9,9,10,10,10,10,10,10,11,11};
__constant__ int TNT[38] = {0,1,2,0,1,2,0,1,2,0,1,2,0,1,2,0,1,2,0,1,2,0,1,2,
                            0,1,2,0,1,2,0,1,2,3,4,5,0,1};

// compile-time copies for fully-unrolled loops
constexpr int cSLOTS[12] = {3,3,3,3,3,3,3,3,3,3,6,2};
constexpr int cFOFFA[12] = {0,3,6,9,12,15,18,21,24,27,30,36};
constexpr int cK5[12]    = {35,35,35,35,35,45,45,45,45,45,85,30};
constexpr int cGOFFC[12] = {0,7,14,21,28,35,44,53,62,71,80,97};
constexpr int cC0[12]    = {3,4,2,1,0,3,4,2,1,0,45,62};
constexpr int cSTP[12]   = {5,5,5,5,5,5,5,5,5,5,1,1};
constexpr int cGCNT[12]  = {7,7,7,7,7,9,9,9,9,9,17,6};

// fp32 workspace region (float offsets)
#define QK_GRP 0        // [12][2][128]
#define QK_ENS 3072     // [24][128]
#define QB_GRP 6144     // [12][2]
#define QB_ENS 6176     // [24]
#define CGRP   6208     // [12][128]
#define CENS   7744     // [128]
// byte offsets
#define CWQ_BYTE   43776    // float [103][2][8]
#define MPL_BYTE   50432    // MA: ushort [12][2][8mt][4kt][64][8]  (786432 B)
#define CW2_BYTE   836864   // CW2: ushort [38tile][4kt][64][8]     (155648 B)
#define MEB_BYTE   1623296  // ushort [8mt][8kt][64][8] (65536 B)
#define QKEB_BYTE  1688832  // ushort [2nt][4kt][64][8] (8192 B)
#define FWS_BYTE   1697024  // ushort 304 frags * 512  (311296 B)

__device__ __forceinline__ float bf2f(unsigned short s) {
  return __uint_as_float(((unsigned)s) << 16);
}
__device__ __forceinline__ unsigned short f2bf(float f) {
  unsigned u = __float_as_uint(f);
  u += 0x7fffu + ((u >> 16) & 1u);
  return (unsigned short)(u >> 16);
}

// ---------------------------------------------------------------------------
// P1 (unchanged from R11). Grid 2242 x 256.
// ---------------------------------------------------------------------------
__global__ void hwe_p1(const float* __restrict__ giw, const float* __restrict__ gib,
                       const float* __restrict__ gow, const float* __restrict__ gob,
                       const float* __restrict__ cq,  const float* __restrict__ eq,
                       const float* __restrict__ eiw, const float* __restrict__ eib,
                       const float* __restrict__ eow, const float* __restrict__ eob,
                       const float* __restrict__ cw,  const float* __restrict__ cb,
                       const float* __restrict__ ce,
                       float* __restrict__ wsf, unsigned short* __restrict__ MA,
                       unsigned short* __restrict__ CW2,
                       unsigned short* __restrict__ MeB, unsigned short* __restrict__ Fws) {
  int blk = blockIdx.x, tid = threadIdx.x;
  int wave = tid >> 6, lane = tid & 63;
  if (blk < 48) {
    __shared__ float qf[64];
    bool ens = blk >= 24;
    int bi = ens ? blk - 24 : blk;
    int i = bi >> 1, h = bi & 1;
    const float* W  = ens ? eiw : giw + i*49152;
    const float* bv = ens ? eib : gib + i*384;
    const float* qv = ens ? eq + i*128 : cq + i*128;
    for (int it = 0; it < 16; ++it) {
      int dp = it*4 + wave;
      const float* wrow = W + (h*64 + dp)*128;
      float acc = wrow[lane]*qv[lane] + wrow[lane+64]*qv[lane+64];
#pragma unroll
      for (int off = 32; off > 0; off >>= 1) acc += __shfl_down(acc, off);
      if (lane == 0) qf[dp] = acc + bv[h*64 + dp];
    }
    __syncthreads();
    if (tid < 128) {
      int e = tid;
      const float* Wk = W + (128 + h*64)*128 + e;
      float a0=0.f,a1=0.f,a2=0.f,a3=0.f;
      for (int dp = 0; dp < 64; dp += 4) {
        a0 += qf[dp+0] * Wk[(dp+0)*128];
        a1 += qf[dp+1] * Wk[(dp+1)*128];
        a2 += qf[dp+2] * Wk[(dp+2)*128];
        a3 += qf[dp+3] * Wk[(dp+3)*128];
      }
      wsf[(ens ? QK_ENS : QK_GRP) + bi*128 + e] = (a0+a1)+(a2+a3);
    }
    if (wave == 3) {
      float acc = qf[lane] * bv[128 + h*64 + lane];
#pragma unroll
      for (int off = 32; off > 0; off >>= 1) acc += __shfl_down(acc, off);
      if (lane == 0) wsf[(ens ? QB_ENS : QB_GRP) + bi] = acc;
    }
  } else if (blk < 1584) {               // MA bf16 A-frags
    int b2 = blk - 48;
    int gi = b2 >> 7, r = b2 & 127;
    int ep = tid, h = ep >> 7, e = ep & 127;
    const float* wo = gow + gi*16384 + r*128 + h*64;
    const float* wv = giw + gi*49152 + (256 + h*64)*128 + e;
    float a0=0.f,a1=0.f,a2=0.f,a3=0.f;
    for (int hd = 0; hd < 64; hd += 4) {
      a0 += wo[hd+0] * wv[(hd+0)*128];
      a1 += wo[hd+1] * wv[(hd+1)*128];
      a2 += wo[hd+2] * wv[(hd+2)*128];
      a3 += wo[hd+3] * wv[(hd+3)*128];
    }
    float acc = (a0+a1)+(a2+a3);
    int mt = r >> 4, lr = r & 15, kt = e >> 5, q = (e >> 3) & 3, j = e & 7;
    MA[(((gi*2 + h)*8 + mt)*4 + kt)*512 + (q*16 + lr)*8 + j] = f2bf(acc);
  } else if (blk < 1712) {               // MeB A-frag
    int f2 = (blk - 1584)*256 + tid;
    int r = f2 >> 8, ep = f2 & 255;
    int h = ep >> 7, e = ep & 127;
    const float* wo = eow + r*128 + h*64;
    const float* wv = eiw + (256 + h*64)*128 + e;
    float a0=0.f,a1=0.f,a2=0.f,a3=0.f;
    for (int hd = 0; hd < 64; hd += 4) {
      a0 += wo[hd+0] * wv[(hd+0)*128];
      a1 += wo[hd+1] * wv[(hd+1)*128];
      a2 += wo[hd+2] * wv[(hd+2)*128];
      a3 += wo[hd+3] * wv[(hd+3)*128];
    }
    float acc = (a0+a1)+(a2+a3);
    int mt = r >> 4, lr = r & 15, kt = ep >> 5, q = (ep >> 3) & 3, j = ep & 7;
    MeB[((mt*8 + kt)*64 + (q*16 + lr))*8 + j] = f2bf(acc);
  } else if (blk < 2096) {               // CGRP
    int id = (blk - 1712)*4 + wave;
    int i = id >> 7, d = id & 127;
    const float* wrow = gow + i*16384 + d*128;
    const float* bvv = gib + i*384 + 256;
    float acc = wrow[lane]*bvv[lane] + wrow[lane+64]*bvv[lane+64];
#pragma unroll
    for (int off = 32; off > 0; off >>= 1) acc += __shfl_down(acc, off);
    if (lane == 0) wsf[CGRP + id] = acc + gob[i*128 + d];
  } else if (blk < 2128) {               // CENS
    int d = (blk - 2096)*4 + wave;
    const float* wrow = eow + d*128;
    const float* bvv = eib + 256;
    float acc = wrow[lane]*bvv[lane] + wrow[lane+64]*bvv[lane+64];
#pragma unroll
    for (int off = 32; off > 0; off >>= 1) acc += __shfl_down(acc, off);
    if (lane == 0) wsf[CENS + d] = acc + eob[d];
  } else if (blk < 2166) {               // CW2 B-frags
    int tile = blk - 2128;
    int gi = TGI[tile], nt = TNT[tile];
    int kt = tid >> 6;
    int l15b = tid & 15, quadb = (tid >> 4) & 3;
    int k = nt*16 + l15b;
    int e = kt*32 + quadb*8;
    unsigned short vv[8];
    if (k < K5A[gi]) {
      int q = (k*205) >> 10;
      int pp = k - q*5;
      int s = GSLOT[GOFF[gi] + q];
      int v = (s < 45) ? s : s + 20;
      if (pp < 4) {
        const float* src = cw + (v*4 + pp)*128 + e;
#pragma unroll
        for (int j = 0; j < 8; ++j) vv[j] = f2bf(src[j]);
      } else {
        const float* b1 = cb + v*128 + e;
        const float* c1 = ce + v*128 + e;
#pragma unroll
        for (int j = 0; j < 8; ++j) vv[j] = f2bf(b1[j] + c1[j]);
      }
    } else {
#pragma unroll
      for (int j = 0; j < 8; ++j) vv[j] = 0;
    }
    unsigned short* dst = CW2 + (tile*4 + kt)*512 + (tid & 63)*8;
#pragma unroll
    for (int j = 0; j < 8; ++j) dst[j] = vv[j];
  } else {                               // F-zero
    int idx = (blk - 2166)*256 + tid;
    if (idx < 19456) ((uint4*)Fws)[idx] = (uint4){0,0,0,0};
  }
}

// ---------------------------------------------------------------------------
// P2 (unchanged from R11). Grid 260 x 256.
// ---------------------------------------------------------------------------
__global__ void hwe_p2(const float* __restrict__ cw, const float* __restrict__ cb,
                       const float* __restrict__ ce,
                       const unsigned short* __restrict__ MA,
                       const unsigned short* __restrict__ CW2,
                       const float* __restrict__ wsf,
                       unsigned short* __restrict__ Fws,
                       unsigned short* __restrict__ qkeB, float* __restrict__ cwq) {
  int blk = blockIdx.x, tid = threadIdx.x;
  int wave = tid >> 6, lane = tid & 63;
  int quad = lane >> 4, l15 = lane & 15;
  if (blk < 192) {
    int gi = blk >> 4, h = (blk >> 3) & 1, mt = blk & 7;
    int K5 = K5A[gi], S = SLOTS3[gi];
    const unsigned short* MAp = MA + (((gi*2 + h)*8 + mt)*4)*512 + lane*8;
    short8 a[4];
#pragma unroll
    for (int kt = 0; kt < 4; ++kt)
      a[kt] = *(const short8*)(MAp + kt*512);
    for (int nt = wave; nt < S; nt += 4) {
      const unsigned short* Bp = CW2 + (FOFFA[gi] + nt)*2048 + lane*8;
      f32x4 acc = {0.f,0.f,0.f,0.f};
#pragma unroll
      for (int kt = 0; kt < 4; ++kt) {
        short8 b = *(const short8*)(Bp + kt*512);
        acc = __builtin_amdgcn_mfma_f32_16x16x32_bf16(a[kt], b, acc, 0, 0, 0);
      }
      int k = nt*16 + l15;
      if (k < K5) {
        int kpp = h*K5 + k;
        int base = (FOFFA[gi]*8 + mt*S + (kpp >> 5))*512
                 + ((kpp >> 3) & 3)*128 + (kpp & 7);
#pragma unroll
        for (int reg = 0; reg < 4; ++reg) {
          int rr = quad*4 + reg;
          Fws[base + rr*8] = f2bf(acc[reg]);
        }
      }
    }
  } else if (blk < 208) {
    int f4 = (blk - 192)*256 + tid;
    int ln = (f4 >> 3) & 63, j = f4 & 7;
    int th = ((f4 >> 11) & 1)*16 + (ln & 15);
    int kt = (f4 >> 9) & 3;
    float val = (th < 24) ? wsf[QK_ENS + th*128 + kt*32 + (ln >> 4)*8 + j] : 0.f;
    qkeB[f4] = f2bf(val);
  } else {
    int wid = (blk - 208)*4 + wave;
    if (wid < 206) {
      int gg = wid >> 1, h = wid & 1;
      int gi = GIDX[gg];
      int s = GSLOT[gg];
      int v = (s < 45) ? s : s + 20;
      const float* qk = wsf + QK_GRP + (gi*2 + h)*128;
      float q0 = qk[lane], q1 = qk[lane + 64];
      float a[5];
#pragma unroll
      for (int pp = 0; pp < 4; ++pp)
        a[pp] = cw[(v*4 + pp)*128 + lane]*q0 + cw[(v*4 + pp)*128 + lane + 64]*q1;
      a[4] = (cb[v*128 + lane] + ce[v*128 + lane])*q0 +
             (cb[v*128 + lane + 64] + ce[v*128 + lane + 64])*q1;
#pragma unroll
      for (int off = 32; off > 0; off >>= 1)
#pragma unroll
        for (int kk = 0; kk < 5; ++kk) a[kk] += __shfl_down(a[kk], off);
      if (lane == 0) {
        float* o = cwq + (gg*2 + h)*8;
        o[0] = a[0]*0.125f; o[1] = a[1]*0.125f; o[2] = a[2]*0.125f; o[3] = a[3]*0.125f;
        o[4] = (a[4] + wsf[QB_GRP + gi*2 + h]) * 0.125f;
      }
    }
  }
}

// ---------------------------------------------------------------------------
// Main kernel. grid 1024, block 256 (4 waves), 8 patches/block.
// LDS 40576 B -> 4 blocks/CU (layout identical to R11).
// ---------------------------------------------------------------------------
__global__ __launch_bounds__(256, 4) void hwe_main(
    const float* __restrict__ x,
    const float* __restrict__ lgam, const float* __restrict__ lbet,
    const float* __restrict__ wsf,  const float* __restrict__ cwq,
    const unsigned short* __restrict__ Fws, const unsigned short* __restrict__ MeB,
    const unsigned short* __restrict__ qkeB,
    float* __restrict__ out) {
  __shared__ __align__(16) unsigned char smem[40576];
  unsigned short* xpB   = (unsigned short*)(smem);
  unsigned short* scb   = (unsigned short*)(smem + 4352);
  unsigned short* wpAll = (unsigned short*)(smem + 7680);
  unsigned short* Gl    = (unsigned short*)(smem);          // C3 overlay
  unsigned short* sce2  = (unsigned short*)(smem + 10240);  // C overlay
  unsigned short* outg2 = (unsigned short*)(smem + 15872);
  float*          stats = (float*)(smem + 40448);           // [2][16]

  const int tid  = threadIdx.x;
  const int wave = tid >> 6;
  const int lane = tid & 63;
  const int quad = lane >> 4;
  const int l15  = lane & 15;

  const int hi   = blockIdx.x >> 4;
  const int wib  = (blockIdx.x & 15) << 3;
  const int nbase = hi*128 + wib;

  // ---- A1: pixels (float2-vectorized) ----
  for (int idx = tid; idx < 1088; idx += 256) {
    int c2 = idx & 7, r = (idx >> 3) & 1, s = idx >> 4;
    int v = (s < 45) ? s : s + 20;
    const float2 xv = *(const float2*)(x + (v*128 + 2*hi + r)*256 + 2*wib + c2*2);
    unsigned pk = (unsigned)f2bf(xv.x) | ((unsigned)f2bf(xv.y) << 16);
    *(unsigned*)(xpB + (c2*68 + s)*4 + r*2) = pk;
  }
  __syncthreads();

  // ---- A2: group scores via cwq fold ----
  for (int idx = tid; idx < 1648; idx += 256) {
    int h = idx & 1, p = (idx >> 1) & 7, gg = idx >> 4;
    int s = GSLOT[gg];
    const float* c = cwq + (gg*2 + h)*8;
    const unsigned short* xr = xpB + (p*68 + s)*4;
    float acc = c[4] + bf2f(xr[0])*c[0] + bf2f(xr[1])*c[1]
                     + bf2f(xr[2])*c[2] + bf2f(xr[3])*c[3];
    scb[(p*2 + h)*104 + gg] = f2bf(acc);
  }
  __syncthreads();

  // ---- A3: softmax per (p,h,group) — register-resident ----
  if (tid < 192) {
    int gi = tid % 12, h = (tid / 12) & 1, p = tid / 24;
    int go = GOFF[gi], G = GOFF[gi+1] - go;
    unsigned short* row = scb + (p*2 + h)*104 + go;
    float ev[17];
    float m = -1e30f;
#pragma unroll
    for (int g = 0; g < 17; ++g) {
      ev[g] = (g < G) ? bf2f(row[g]) : -1e30f;
      m = fmaxf(m, ev[g]);
    }
    float ssum = 0.f;
#pragma unroll
    for (int g = 0; g < 17; ++g) {
      float e = __expf(ev[g] - m);
      ev[g] = e;
      if (g < G) ssum += e;
    }
    float inv = 1.f / ssum;
#pragma unroll
    for (int g = 0; g < 17; ++g)
      if (g < G) row[g] = f2bf(ev[g] * inv);
  }
  __syncthreads();

  // ---- Phase B: 6 phases x 2 groups; task-major fill + F-folded GEMM ----
  {
    short8 fA[6], fB[6];
    float4 cgA, cgB;
    auto fws_issue = [&](int gi, int mh, short8 (&buf)[6], float4& cg) {
      int S = cSLOTS[gi];
      int mt = mh*4 + wave;
      const unsigned short* fp = Fws + (cFOFFA[gi]*8 + mt*S)*512 + lane*8;
#pragma unroll
      for (int kt = 0; kt < 6; ++kt)
        if (kt < S) buf[kt] = *(const short8*)(fp + kt*512);
      cg = *(const float4*)(wsf + CGRP + gi*128 + mt*16 + quad*4);
    };
    auto fws_compute = [&](int gi, int mh, int lbase, short8 (&buf)[6],
                           const float4& cg) {
      int S = cSLOTS[gi];
      int mt = mh*4 + wave;
      f32x4 acc = {0.f,0.f,0.f,0.f};
#pragma unroll
      for (int kt = 0; kt < 6; ++kt)
        if (kt < S) {
          short8 b = *(const short8*)(wpAll + (lbase + kt)*512 + lane*8);
          acc = __builtin_amdgcn_mfma_f32_16x16x32_bf16(buf[kt], b, acc, 0, 0, 0);
        }
      if (l15 < 8) {
        int p = l15;
        int rb = mt*16 + quad*4;
        unsigned short t0 = f2bf(acc[0] + cg.x);
        unsigned short t1 = f2bf(acc[1] + cg.y);
        unsigned short t2 = f2bf(acc[2] + cg.z);
        unsigned short t3 = f2bf(acc[3] + cg.w);
        uint2 w;
        w.x = (unsigned)t0 | ((unsigned)t1 << 16);
        w.y = (unsigned)t2 | ((unsigned)t3 << 16);
        int row = gi*8 + p;
        int ch = (rb >> 3) ^ ((gi ^ p) & 7);      // dual-key swizzle
        *(uint2*)(outg2 + row*128 + ch*8 + (rb & 7)) = w;
      }
    };

    fws_issue(0, 0, fA, cgA);    // prologue prefetch

#pragma unroll
    for (int ph = 0; ph < 6; ++ph) {
      const int g0 = 2*ph;
      const int S0 = cSLOTS[g0];

      // ---- precise tail-zero: kpp in [2*K5, S*32), all 16 pf ----
      {
        const int T0 = cSLOTS[g0]*32   - 2*cK5[g0];
        const int T1 = cSLOTS[g0+1]*32 - 2*cK5[g0+1];
        const int ntz = (T0 + T1)*16;
        for (int t = tid; t < ntz; t += 256) {
          bool gs = (t >= T0*16);
          int tt  = gs ? t - T0*16 : t;
          int kpp = (gs ? 2*cK5[g0+1] : 2*cK5[g0]) + (tt >> 4);
          int pf  = tt & 15;
          int lb  = gs ? S0 : 0;
          int pos = (lb + (kpp >> 5))*512 + ((kpp >> 3) & 3)*128 + pf*8 + (kpp & 7);
          wpAll[pos] = 0;
        }
      }

      // ---- task-major fill: task=(group,q,h,p) -> 5 values ----
      {
        const int G0 = cGCNT[g0], G1 = cGCNT[g0+1];
        const int ntask = (G0 + G1)*16;
        for (int t = tid; t < ntask; t += 256) {
          bool gs = (t >= G0*16);
          int tt  = gs ? t - G0*16 : t;
          int K5    = gs ? cK5[g0+1]    : cK5[g0];
          int goffB = gs ? cGOFFC[g0+1] : cGOFFC[g0];
          int c0    = gs ? cC0[g0+1]    : cC0[g0];
          int stp   = gs ? cSTP[g0+1]   : cSTP[g0];
          int lbase = gs ? S0 : 0;
          int q = tt >> 4;
          int h = (tt >> 3) & 1;
          int p = tt & 7;
          unsigned short araw = scb[(p*2 + h)*104 + goffB + q];
          float a = bf2f(araw);
          int s = c0 + q*stp;
          uint2 xw = *(const uint2*)(xpB + (p*68 + s)*4);
          unsigned short o0 = f2bf(a * bf2f((unsigned short)(xw.x & 0xffffu)));
          unsigned short o1 = f2bf(a * bf2f((unsigned short)(xw.x >> 16)));
          unsigned short o2 = f2bf(a * bf2f((unsigned short)(xw.y & 0xffffu)));
          unsigned short o3 = f2bf(a * bf2f((unsigned short)(xw.y >> 16)));
          int kpp0 = h*K5 + q*5;
          // pos walks +1 per kpp, +121 when j wraps (7 -> 0)
          int pos = (lbase + (kpp0 >> 5))*512 + ((kpp0 >> 3) & 3)*128
                  + p*8 + (kpp0 & 7);
          wpAll[pos] = o0;
          pos += ((kpp0 & 7) == 7) ? 121 : 1;
          wpAll[pos] = o1;
          pos += (((kpp0+1) & 7) == 7) ? 121 : 1;
          wpAll[pos] = o2;
          pos += (((kpp0+2) & 7) == 7) ? 121 : 1;
          wpAll[pos] = o3;
          pos += (((kpp0+3) & 7) == 7) ? 121 : 1;
          wpAll[pos] = araw;                     // pp=4 bias term: val = a
        }
      }
      __syncthreads();                       // fill visible

      fws_issue(g0+0, 1, fB, cgB);
      fws_compute(g0+0, 0, 0,  fA, cgA);
      fws_issue(g0+1, 0, fA, cgA);
      fws_compute(g0+0, 1, 0,  fB, cgB);
      fws_issue(g0+1, 1, fB, cgB);
      fws_compute(g0+1, 0, S0, fA, cgA);
      if (ph < 5) fws_issue(g0+2, 0, fA, cgA);   // cross-phase prefetch
      fws_compute(g0+1, 1, S0, fB, cgB);
      __syncthreads();                       // wpAll consumed
    }
  }

  // preload cens + MeB fragments early (hide latency under C1/C2)
  float cens0[4], cens1[4];
  {
    float4 c0 = *(const float4*)(wsf + CENS + (wave*2 + 0)*16 + quad*4);
    float4 c1 = *(const float4*)(wsf + CENS + (wave*2 + 1)*16 + quad*4);
    cens0[0]=c0.x; cens0[1]=c0.y; cens0[2]=c0.z; cens0[3]=c0.w;
    cens1[0]=c1.x; cens1[1]=c1.y; cens1[2]=c1.z; cens1[3]=c1.w;
  }
  short8 meAr[16];   // [mi][h][kt]
#pragma unroll
  for (int mi = 0; mi < 2; ++mi)
#pragma unroll
    for (int h = 0; h < 2; ++h)
#pragma unroll
      for (int kt = 0; kt < 4; ++kt)
        meAr[(mi*2 + h)*4 + kt] =
          *(const short8*)(MeB + (((wave*2 + mi)*8 + h*4 + kt)*64 + lane)*8);

  // ---- C1: ens scores GEMM (M=96 rows (s,p), N=24 (t,h), K=128) ----
#pragma unroll
  for (int ti = 0; ti < 3; ++ti) {
    int T = wave*3 + ti;
    int mtp = T >> 1, ntp = T & 1;
    int rowA = mtp*16 + l15;
    int sx = ((rowA >> 3) ^ rowA) & 7;
    f32x4 acc = {0.f,0.f,0.f,0.f};
#pragma unroll
    for (int kt = 0; kt < 4; ++kt) {
      short8 a = *(const short8*)(outg2 + rowA*128 + (((kt*4 + quad) ^ sx) << 3));
      short8 b = *(const short8*)(qkeB + ((ntp*4 + kt)*64 + lane)*8);
      acc = __builtin_amdgcn_mfma_f32_16x16x32_bf16(a, b, acc, 0, 0, 0);
    }
    int th = ntp*16 + l15;
    if (th < 24) {
      float qb = wsf[QB_ENS + th];
#pragma unroll
      for (int reg = 0; reg < 4; ++reg) {
        int rowE = mtp*16 + quad*4 + reg;
        sce2[((rowE & 7)*24 + th)*12 + (rowE >> 3)] = f2bf((acc[reg] + qb) * 0.125f);
      }
    }
  }
  __syncthreads();

  // ---- C2: softmax over s per (p, t, h) — register-resident ----
  if (tid < 192) {
    unsigned short* row = sce2 + tid*12;
    float ev[12];
    float m = -1e30f;
#pragma unroll
    for (int s = 0; s < 12; ++s) { ev[s] = bf2f(row[s]); m = fmaxf(m, ev[s]); }
    float ssum = 0.f;
#pragma unroll
    for (int s = 0; s < 12; ++s) { float e = __expf(ev[s] - m); ev[s] = e; ssum += e; }
    float inv = 1.f / ssum;
#pragma unroll
    for (int s = 0; s < 12; ++s) row[s] = f2bf(ev[s] * inv);
  }
  __syncthreads();

  // ---- C3: 2 patches/period: G-GEMM -> Gl transpose (intra-wave) ->
  //      bfrag gather from sce2 -> R-GEMM -> register LayerNorm ----
  for (int pp2 = 0; pp2 < 4; ++pp2) {
    f32x4 g[2][2][2];  // [lp][mi][h]
#pragma unroll
    for (int lp = 0; lp < 2; ++lp)
#pragma unroll
      for (int mi = 0; mi < 2; ++mi)
#pragma unroll
        for (int h = 0; h < 2; ++h) g[lp][mi][h] = (f32x4){0.f,0.f,0.f,0.f};
#pragma unroll
    for (int lp = 0; lp < 2; ++lp) {
      int p = pp2*2 + lp;
      int brow = (l15 < 12) ? (l15*8 + p) : 0;   // clamp; zeroed below
      int sx = ((brow >> 3) ^ brow) & 7;
#pragma unroll
      for (int h = 0; h < 2; ++h) {
#pragma unroll
        for (int kt = 0; kt < 4; ++kt) {
          short8 b = *(const short8*)(outg2 + brow*128 + (((kt*4 + quad) ^ sx) << 3));
          if (l15 >= 12) b = (short8){0,0,0,0,0,0,0,0};
          g[lp][0][h] = __builtin_amdgcn_mfma_f32_16x16x32_bf16(
              meAr[(0*2 + h)*4 + kt], b, g[lp][0][h], 0, 0, 0);
          g[lp][1][h] = __builtin_amdgcn_mfma_f32_16x16x32_bf16(
              meAr[(1*2 + h)*4 + kt], b, g[lp][1][h], 0, 0, 0);
        }
      }
    }

    f32x4 rr[2][2];
    float s1[2] = {0.f, 0.f}, s2[2] = {0.f, 0.f};
#pragma unroll
    for (int lp = 0; lp < 2; ++lp) {
      int p = pp2*2 + lp;
#pragma unroll
      for (int mi = 0; mi < 2; ++mi)
#pragma unroll
        for (int h = 0; h < 2; ++h)
#pragma unroll
          for (int reg = 0; reg < 4; ++reg) {
            int r = (wave*2 + mi)*16 + quad*4 + reg;
            Gl[r*40 + h*16 + l15] = f2bf(g[lp][mi][h][reg]);
          }
      short8 af0 = *(const short8*)(Gl + ((wave*2 + 0)*16 + l15)*40 + quad*8);
      short8 af1 = *(const short8*)(Gl + ((wave*2 + 1)*16 + l15)*40 + quad*8);
      union { short8 s8; uint4 u4; } bu;
      {
        const unsigned short* sp = sce2 + (p*24 + l15*2 + (quad >> 1))*12 + (quad & 1)*8;
        uint2 lo = *(const uint2*)(sp);
        uint2 hi2 = *(const uint2*)(sp + 4);
        if (quad & 1) { hi2.x = 0u; hi2.y = 0u; }          // s=12..15 -> 0
        if (l15 >= 12) { lo.x = 0u; lo.y = 0u; hi2.x = 0u; hi2.y = 0u; }
        bu.u4.x = lo.x; bu.u4.y = lo.y; bu.u4.z = hi2.x; bu.u4.w = hi2.y;
      }
#pragma unroll
      for (int mi = 0; mi < 2; ++mi) {
        f32x4 acc = {0.f,0.f,0.f,0.f};
        acc = __builtin_amdgcn_mfma_f32_16x16x32_bf16(mi ? af1 : af0, bu.s8,
                                                      acc, 0, 0, 0);
#pragma unroll
        for (int reg = 0; reg < 4; ++reg)
          acc[reg] += (mi ? cens1[reg] : cens0[reg]);
        rr[lp][mi] = acc;
        if (l15 < 12) {
#pragma unroll
          for (int reg = 0; reg < 4; ++reg) {
            float v = acc[reg];
            s1[lp] += v; s2[lp] += v*v;
          }
        }
      }
    }
#pragma unroll
    for (int off = 32; off > 0; off >>= 1) {
#pragma unroll
      for (int lp = 0; lp < 2; ++lp) {
        s1[lp] += __shfl_xor(s1[lp], off);
        s2[lp] += __shfl_xor(s2[lp], off);
      }
    }
    int sb = (pp2 & 1) << 4;               // stats double-buffer
    if (lane == 0) {
#pragma unroll
      for (int lp = 0; lp < 2; ++lp) {
        stats[sb + lp*4 + wave] = s1[lp];
        stats[sb + 8 + lp*4 + wave] = s2[lp];
      }
    }
    __syncthreads();
#pragma unroll
    for (int lp = 0; lp < 2; ++lp) {
      float t1 = stats[sb+lp*4+0] + stats[sb+lp*4+1] + stats[sb+lp*4+2] + stats[sb+lp*4+3];
      float t2 = stats[sb+8+lp*4+0] + stats[sb+8+lp*4+1] + stats[sb+8+lp*4+2] + stats[sb+8+lp*4+3];
      float mean = t1 * (1.f/1536.f);
      float var  = t2 * (1.f/1536.f) - mean*mean;
      float rstd = rsqrtf(var + 1e-5f);
      if (l15 < 12) {
        long nrow = (long)(nbase + pp2*2 + lp) * 1536;
#pragma unroll
        for (int mi = 0; mi < 2; ++mi) {
          int rb = (wave*2 + mi)*16 + quad*4;
          int j = l15*128 + rb;
          float4 gm = *(const float4*)(lgam + j);
          float4 bt = *(const float4*)(lbet + j);
          float4 o;
          o.x = (rr[lp][mi][0] - mean)*rstd*gm.x + bt.x;
          o.y = (rr[lp][mi][1] - mean)*rstd*gm.y + bt.y;
          o.z = (rr[lp][mi][2] - mean)*rstd*gm.z + bt.z;
          o.w = (rr[lp][mi][3] - mean)*rstd*gm.w + bt.w;
          *(float4*)(out + nrow + j) = o;
        }
      }
    }
  }
}

// ---------------------------------------------------------------------------
extern "C" void kernel_launch(void* const* d_in, const int* in_sizes, int n_in,
                              void* d_out, int out_size, void* d_ws, size_t ws_size,
                              hipStream_t stream) {
  const float* x   = (const float*)d_in[0];
  const float* cw  = (const float*)d_in[1];
  const float* cb  = (const float*)d_in[2];
  const float* ce  = (const float*)d_in[3];
  const float* cq  = (const float*)d_in[4];
  const float* giw = (const float*)d_in[5];
  const float* gib = (const float*)d_in[6];
  const float* gow = (const float*)d_in[7];
  const float* gob = (const float*)d_in[8];
  const float* eq  = (const float*)d_in[9];
  const float* eiw = (const float*)d_in[10];
  const float* eib = (const float*)d_in[11];
  const float* eow = (const float*)d_in[12];
  const float* eob = (const float*)d_in[13];
  const float* lg  = (const float*)d_in[14];
  const float* lb  = (const float*)d_in[15];

  float* wsf = (float*)d_ws;
  float* cwq = (float*)((char*)d_ws + CWQ_BYTE);
  unsigned short* MA   = (unsigned short*)((char*)d_ws + MPL_BYTE);
  unsigned short* CW2  = (unsigned short*)((char*)d_ws + CW2_BYTE);
  unsigned short* MeB  = (unsigned short*)((char*)d_ws + MEB_BYTE);
  unsigned short* qkeB = (unsigned short*)((char*)d_ws + QKEB_BYTE);
  unsigned short* Fws  = (unsigned short*)((char*)d_ws + FWS_BYTE);

  hwe_p1<<<2242, 256, 0, stream>>>(giw, gib, gow, gob, cq, eq, eiw, eib, eow, eob,
                                   cw, cb, ce, wsf, MA, CW2, MeB, Fws);
  hwe_p2<<<260, 256, 0, stream>>>(cw, cb, ce, MA, CW2, wsf, Fws, qkeB, cwq);
  hwe_main<<<1024, 256, 0, stream>>>(x, lg, lb, wsf, cwq, Fws, MeB, qkeB,
                                     (float*)d_out);
}